// Round 9
// baseline (123.161 us; speedup 1.0000x reference)
//
#include <hip/hip_runtime.h>
#include <math.h>

#define BB 8
#define CC 64
#define OO 64
#define HH 128
#define WW 128
#define PP 9
#define HWIMG 16384           // H*W per batch
#define NTOT  131072          // B*H*W

typedef __attribute__((ext_vector_type(8))) _Float16 h8;
typedef __attribute__((ext_vector_type(2))) _Float16 h2;
typedef __attribute__((ext_vector_type(4))) float f32x4;

// ---------------------------------------------------------------------------
// Kernel 0: prep (round-6 verbatim). blocks 0..143: wtf[p][o][c] f16.
// block 144: dwt[tap][c], bnA[c], bnB[c].
// ---------------------------------------------------------------------------
__global__ void k_prep(const float* __restrict__ w,
                       const float* __restrict__ dw_w,
                       const float* __restrict__ dw_b,
                       const float* __restrict__ gamma,
                       const float* __restrict__ beta,
                       const float* __restrict__ mean,
                       const float* __restrict__ var,
                       _Float16* __restrict__ wtf,
                       float* __restrict__ dwt,
                       float* __restrict__ bnA,
                       float* __restrict__ bnB) {
  int bid = blockIdx.x, t = threadIdx.x;
  if (bid < 144) {
    int i = bid * 256 + t;
    int c = i & 63, o = (i >> 6) & 63, p = i >> 12;
    wtf[i] = (_Float16)w[(o * 64 + c) * 9 + p];
  } else {
    if (t < 64) {
      float A = gamma[t] * rsqrtf(var[t] + 1e-5f);
      bnA[t] = A;
      bnB[t] = (dw_b[t] - mean[t]) * A + beta[t];
    }
    for (int i = t; i < 576; i += 256) {
      int tap = i % 9, c = i / 9;
      dwt[tap * 64 + c] = dw_w[c * 9 + tap];
    }
  }
}

// ---------------------------------------------------------------------------
// Kernel 1: x NCHW f32 -> xt[b][pix][c] f16 (NHWC) (round-6 verbatim)
// ---------------------------------------------------------------------------
__global__ void __launch_bounds__(256, 4)
k_tr(const float* __restrict__ x, _Float16* __restrict__ xt) {
  __shared__ _Float16 lt[64][66];
  int bid = blockIdx.x;
  int vbid = (bid & 7) * 256 + (bid >> 3);    // XCD k <- batch k
  int tid = threadIdx.x;
  int wid = tid >> 6, ln = tid & 63;
  int b = vbid >> 8;
  int pix0 = (vbid & 255) * 64;
  const float* xbb = x + (size_t)b * CC * HWIMG;

  #pragma unroll
  for (int i = 0; i < 8; ++i) {
    int c0 = (wid * 8 + i) * 2;
    float v0 = xbb[(size_t)c0 * HWIMG + pix0 + ln];
    float v1 = xbb[(size_t)(c0 + 1) * HWIMG + pix0 + ln];
    h2 hv;
    hv[0] = (_Float16)v0;
    hv[1] = (_Float16)v1;
    *(h2*)&lt[ln][c0] = hv;
  }
  __syncthreads();

  int pq = tid >> 2, q = tid & 3;
  h8 o0, o1;
  #pragma unroll
  for (int j = 0; j < 4; ++j) {
    h2 v = *(h2*)&lt[pq][q * 16 + 2 * j];
    o0[2 * j] = v[0];
    o0[2 * j + 1] = v[1];
  }
  #pragma unroll
  for (int j = 0; j < 4; ++j) {
    h2 v = *(h2*)&lt[pq][q * 16 + 8 + 2 * j];
    o1[2 * j] = v[0];
    o1[2 * j + 1] = v[1];
  }
  _Float16* op = xt + ((size_t)((b << 14) + pix0 + pq)) * 64 + q * 16;
  *(h8*)op = o0;
  *(h8*)(op + 8) = o1;
}

// ---------------------------------------------------------------------------
// Kernel 2: offsets (round-6 body, f32 path). Only the store changed:
// packed float2 (sy,sx) per (p, pixel):  soff2[p*NTOT + idx] = {sy, sx}.
// ---------------------------------------------------------------------------
__global__ void __launch_bounds__(256, 3)
k_off2(const _Float16* __restrict__ xt,
       const float* __restrict__ dwt,
       const float* __restrict__ bnA,
       const float* __restrict__ bnB,
       const float* __restrict__ pw_w,
       const float* __restrict__ pw_b,
       float2* __restrict__ soff2) {
  __shared__ __attribute__((aligned(16))) char lsm[324 * 128];
  int bid = blockIdx.x;
  int b = bid & 7, t = bid >> 3;           // XCD k <- batch k
  int ty0 = (t >> 3) * 16, tx0 = (t & 7) * 16;
  int tid = threadIdx.x;
  const _Float16* xb = xt + (((size_t)b) << 14) * 64;

  for (int ch = tid; ch < 2592; ch += 256) {
    int rec = ch >> 3, j = ch & 7;
    int ry = rec / 18, rx = rec - ry * 18;
    int yy = ty0 - 1 + ry, xx = tx0 - 1 + rx;
    bool in = (yy >= 0) & (yy < HH) & (xx >= 0) & (xx < WW);
    h8 v = (h8)(_Float16)0.f;
    if (in) v = *((const h8*)(xb + ((size_t)((yy << 7) + xx)) * 64) + (j ^ (rec & 7)));
    *(h8*)(lsm + rec * 128 + j * 16) = v;
  }
  __syncthreads();

  int qy = tid >> 4, qx = tid & 15;
  float s[CC];
  #pragma unroll
  for (int c = 0; c < CC; ++c) s[c] = 0.f;

  #pragma unroll
  for (int tap = 0; tap < 9; ++tap) {
    int dy = tap / 3 - 1, dx = tap % 3 - 1;
    int rec = (qy + dy + 1) * 18 + (qx + dx + 1);
    #pragma unroll
    for (int g = 0; g < 8; ++g) {
      h8 v = *(const h8*)(lsm + rec * 128 + ((g ^ (rec & 7)) << 4));
      #pragma unroll
      for (int e = 0; e < 8; ++e)
        s[g * 8 + e] += dwt[tap * 64 + g * 8 + e] * (float)v[e];
    }
  }

  #pragma unroll
  for (int c = 0; c < CC; ++c) {
    float v = s[c] * bnA[c] + bnB[c];
    s[c] = v / (1.f + __expf(-v));
  }

  float off[2 * PP];
  #pragma unroll
  for (int k = 0; k < 2 * PP; ++k) {
    float a = pw_b[k];
    #pragma unroll
    for (int c = 0; c < CC; ++c) a += pw_w[k * CC + c] * s[c];
    off[k] = a;
  }

  int y = ty0 + qy, xw = tx0 + qx;
  size_t idx = (size_t)(b << 14) + (y << 7) + xw;
  float fy = (float)y, fx = (float)xw;
  #pragma unroll
  for (int p = 0; p < PP; ++p) {
    float2 v;
    v.x = fy + off[2 * p]     + (float)(p / 3 - 1);
    v.y = fx + off[2 * p + 1] + (float)(p % 3 - 1);
    soff2[(size_t)p * NTOT + idx] = v;
  }
}

// ---------------------------------------------------------------------------
// Kernel 3: gather+MFMA. Round-6 DATAPATH (weights/indices derived in-kernel
// from soff, identical formulas) + round-7 SCHEDULE (512 thr, 8 waves x 1 row,
// 1 px/thread, LA/LB 2-deep ds_read pipeline). Halo 12x20 records in LDS.
// ---------------------------------------------------------------------------
__global__ void __launch_bounds__(512, 2)
k_main(const _Float16* __restrict__ xt,
       const float2* __restrict__ soff2,
       const _Float16* __restrict__ wtf,
       const float* __restrict__ bias,
       float* __restrict__ out) {
  __shared__ __attribute__((aligned(16))) char smem[240 * 128];
  int bid = blockIdx.x;
  int b = bid & 7, t = bid >> 3;            // XCD k <- batch k; 128 tiles/img
  int ty0 = (t >> 3) * 8, tx0 = (t & 7) * 16;
  int tid = threadIdx.x, wid = tid >> 6, ln = tid & 63;
  int lm = ln & 15, lk = ln >> 4;
  const _Float16* xb = xt + (((size_t)b) << 14) * 64;

  int row = ty0 + wid;
  int pix = (row << 7) + tx0 + lm;
  size_t ng = (size_t)(b << 14) + pix;

  // ---- preload all 9 sample coords (issued before staging)
  float sy[PP], sx[PP];
  #pragma unroll
  for (int p = 0; p < PP; ++p) {
    float2 v = soff2[(size_t)p * NTOT + ng];
    sy[p] = v.x;
    sx[p] = v.y;
  }

  // ---- stage 12x20 halo records (clamped), chunk-swizzled
  for (int ch = tid; ch < 1920; ch += 512) {
    int rec = ch >> 3, j = ch & 7;
    int ry = rec / 20, rx = rec - ry * 20;
    int yy = min(max(ty0 - 2 + ry, 0), HH - 1);
    int xx = min(max(tx0 - 2 + rx, 0), WW - 1);
    h8 v = *((const h8*)(xb + ((size_t)((yy << 7) + xx)) * 64) + (j ^ (rec & 7)));
    *(h8*)(smem + rec * 128 + j * 16) = v;
  }
  __syncthreads();

  f32x4 acc[4];
  #pragma unroll
  for (int mt = 0; mt < 4; ++mt) acc[mt] = (f32x4){0.f, 0.f, 0.f, 0.f};

  const _Float16* wl = wtf + lm * 64 + lk * 8;

// Derive weights + halo addresses for point pidx (round-6 verified math),
// issue the 8 ds_reads into dst, stash the 4 weights in W[4].
#define LOADP(dst, W, pidx)                                                   \
  {                                                                           \
    float y0f = floorf(sy[pidx]), x0f = floorf(sx[pidx]);                     \
    float wy1 = sy[pidx] - y0f, wy0 = 1.f - wy1;                              \
    float wx1 = sx[pidx] - x0f, wx0 = 1.f - wx1;                              \
    int y0 = (int)y0f, x0i = (int)x0f;                                        \
    bool vy0 = (y0 >= 0) & (y0 < HH);                                         \
    bool vy1 = (y0 + 1 >= 0) & (y0 + 1 < HH);                                 \
    bool vx0 = (x0i >= 0) & (x0i < WW);                                       \
    bool vx1 = (x0i + 1 >= 0) & (x0i + 1 < WW);                               \
    W[0] = (vy0 && vx0) ? wy0 * wx0 : 0.f;                                    \
    W[1] = (vy0 && vx1) ? wy0 * wx1 : 0.f;                                    \
    W[2] = (vy1 && vx0) ? wy1 * wx0 : 0.f;                                    \
    W[3] = (vy1 && vx1) ? wy1 * wx1 : 0.f;                                    \
    int iy0 = min(max(y0 - ty0 + 2, 0), 10);                                  \
    int ix0 = min(max(x0i - tx0 + 2, 0), 18);                                 \
    int r00 = iy0 * 20 + ix0;                                                 \
    const char* base_ = smem + r00 * 128;                                     \
    dst[0] = *(const h8*)(base_ + ((lk ^ (r00 & 7)) << 4));                   \
    dst[1] = *(const h8*)(base_ + (((lk + 4) ^ (r00 & 7)) << 4));             \
    dst[2] = *(const h8*)(base_ + 128 + ((lk ^ ((r00 + 1) & 7)) << 4));       \
    dst[3] = *(const h8*)(base_ + 128 + (((lk + 4) ^ ((r00 + 1) & 7)) << 4)); \
    dst[4] = *(const h8*)(base_ + 2560 + ((lk ^ ((r00 + 20) & 7)) << 4));     \
    dst[5] = *(const h8*)(base_ + 2560 + (((lk + 4) ^ ((r00 + 20) & 7)) << 4));\
    dst[6] = *(const h8*)(base_ + 2688 + ((lk ^ ((r00 + 21) & 7)) << 4));     \
    dst[7] = *(const h8*)(base_ + 2688 + (((lk + 4) ^ ((r00 + 21) & 7)) << 4));\
  }

#define STEP(pcur, Lcur, Wcur, Lnext, Wnext)                                  \
  {                                                                           \
    if (pcur + 1 < PP) LOADP(Lnext, Wnext, pcur + 1);                         \
    h8 w00v = (h8)(_Float16)Wcur[0];                                          \
    h8 w01v = (h8)(_Float16)Wcur[1];                                          \
    h8 w10v = (h8)(_Float16)Wcur[2];                                          \
    h8 w11v = (h8)(_Float16)Wcur[3];                                          \
    h8 bb0 = Lcur[0] * w00v + Lcur[2] * w01v + Lcur[4] * w10v + Lcur[6] * w11v;\
    h8 bb1 = Lcur[1] * w00v + Lcur[3] * w01v + Lcur[5] * w10v + Lcur[7] * w11v;\
    const _Float16* wp_ = wl + pcur * 4096;                                   \
    _Pragma("unroll")                                                         \
    for (int mt = 0; mt < 4; ++mt) {                                          \
      h8 a0 = *(const h8*)(wp_ + mt * 1024);                                  \
      h8 a1 = *(const h8*)(wp_ + mt * 1024 + 32);                             \
      acc[mt] = __builtin_amdgcn_mfma_f32_16x16x32_f16(a0, bb0, acc[mt], 0, 0, 0); \
      acc[mt] = __builtin_amdgcn_mfma_f32_16x16x32_f16(a1, bb1, acc[mt], 0, 0, 0); \
    }                                                                         \
  }

  h8 LA[8], LB[8];
  float WA[4], WB[4];
  LOADP(LA, WA, 0);
  STEP(0, LA, WA, LB, WB)
  STEP(1, LB, WB, LA, WA)
  STEP(2, LA, WA, LB, WB)
  STEP(3, LB, WB, LA, WA)
  STEP(4, LA, WA, LB, WB)
  STEP(5, LB, WB, LA, WA)
  STEP(6, LA, WA, LB, WB)
  STEP(7, LB, WB, LA, WA)
  STEP(8, LA, WA, LB, WB)

#undef STEP
#undef LOADP

  // ---- epilogue: C/D layout col=lane&15 (pixel), row=(lane>>4)*4+reg (m)
  #pragma unroll
  for (int mt = 0; mt < 4; ++mt) {
    #pragma unroll
    for (int r = 0; r < 4; ++r) {
      int m = mt * 16 + lk * 4 + r;
      out[((size_t)b * OO + m) * HWIMG + pix] = acc[mt][r] + bias[m];
    }
  }
}

// ---------------------------------------------------------------------------
extern "C" void kernel_launch(void* const* d_in, const int* in_sizes, int n_in,
                              void* d_out, int out_size, void* d_ws, size_t ws_size,
                              hipStream_t stream) {
  const float* x        = (const float*)d_in[0];
  const float* dw_w     = (const float*)d_in[1];
  const float* dw_b     = (const float*)d_in[2];
  const float* bn_gamma = (const float*)d_in[3];
  const float* bn_beta  = (const float*)d_in[4];
  const float* bn_mean  = (const float*)d_in[5];
  const float* bn_var   = (const float*)d_in[6];
  const float* pw_w     = (const float*)d_in[7];
  const float* pw_b     = (const float*)d_in[8];
  const float* weight   = (const float*)d_in[9];
  const float* bias     = (const float*)d_in[10];
  float* out = (float*)d_out;

  char* ws = (char*)d_ws;
  float2* soff2 = (float2*)ws;                                 // 9*NTOT*8 = 9.44 MB
  size_t o1 = (size_t)PP * NTOT * 8;
  _Float16* wtf = (_Float16*)(ws + o1);                        // 73728 B
  size_t o2 = o1 + (size_t)PP * OO * CC * 2;
  _Float16* xtb = (_Float16*)(ws + o2);                        // 16.8 MB
  size_t o3 = o2 + (size_t)NTOT * CC * 2;
  float* dwt = (float*)(ws + o3);                              // 2304 B
  float* bnA = (float*)(ws + o3 + 2304);
  float* bnB = (float*)(ws + o3 + 2304 + 256);

  k_prep<<<145, 256, 0, stream>>>(weight, dw_w, dw_b, bn_gamma, bn_beta,
                                  bn_mean, bn_var, wtf, dwt, bnA, bnB);
  k_tr<<<NTOT / 64, 256, 0, stream>>>(x, xtb);
  k_off2<<<NTOT / 256, 256, 0, stream>>>(xtb, dwt, bnA, bnB, pw_w, pw_b, soff2);
  k_main<<<NTOT / 128, 512, 0, stream>>>(xtb, soff2, wtf, bias, out);
}